// Round 1
// baseline (721.352 us; speedup 1.0000x reference)
//
#include <hip/hip_runtime.h>

typedef __attribute__((ext_vector_type(8))) short bf16x8;
typedef __attribute__((ext_vector_type(4))) float f32x4;

#define DEVINL __device__ __forceinline__
#define AS1 __attribute__((address_space(1)))
#define AS3 __attribute__((address_space(3)))

constexpr int BB = 4, SS = 4096, DD = 1024, LL = 8192;
constexpr int LT = 128, ST = 128, BK = 64, NS = 2;
constexpr int NL = LL / LT;        // 64 l-tiles
constexpr int SCHUNK = SS / NS;    // 2048 s per block
constexpr int NST = SCHUNK / ST;   // 16 s-tiles per block
constexpr int KST = DD / BK;       // 16 k-steps
constexpr int TILE = LT * BK;      // 8192 bf16 elems = 16 KiB per tile

DEVINL unsigned short f2bf(float f){
  union { float f; unsigned u; } a; a.f = f;
  unsigned r = a.u + 0x7fffu + ((a.u >> 16) & 1u);   // RNE
  return (unsigned short)(r >> 16);
}

DEVINL void gll16(const void* src, void* dst){
  __builtin_amdgcn_global_load_lds((const AS1 unsigned int*)src,
                                   (AS3 unsigned int*)dst, 16, 0, 0);
}

// Stage a [128 x 64] bf16 tile (row stride DD) into LDS.
// LDS dest is LINEAR (global_load_lds requirement); the xor-swizzle
// (slot ^= row&7) is applied on the per-lane GLOBAL source address, and the
// identical xor is applied on ds_read (read_frag) -> bank-conflict-free.
DEVINL void stage_tile(const unsigned short* __restrict__ g0, int row0, int d0,
                       unsigned short* ldsbase, int wave, int lane){
#pragma unroll
  for (int it = 0; it < 4; ++it){
    int off  = it*4096 + wave*1024 + lane*16;   // byte offset inside tile
    int row  = off >> 7;                        // 128 B per row
    int slot = (off >> 4) & 7;
    int scol = (slot ^ (row & 7)) << 3;         // swizzled 8-elem chunk
    gll16(g0 + (size_t)(row0 + row) * DD + d0 + scol,
          ldsbase + ((it*4096 + wave*1024) >> 1));
  }
}

// read one MFMA operand fragment: 8 contiguous bf16 at (row, 8-elem chunk)
DEVINL bf16x8 read_frag(const unsigned short* tile, int row, int chunk){
  return *(const AS3 bf16x8*)(tile + row*BK + ((chunk ^ (row & 7)) << 3));
}

__global__ void conv_kernel(const float4* __restrict__ in,
                            ushort4* __restrict__ out, int n4){
  int stride = gridDim.x * blockDim.x;
  for (int i = blockIdx.x*blockDim.x + threadIdx.x; i < n4; i += stride){
    float4 v = in[i];
    ushort4 o;
    o.x = f2bf(v.x); o.y = f2bf(v.y); o.z = f2bf(v.z); o.w = f2bf(v.w);
    out[i] = o;
  }
}

// Z[bs,e] = tanh( X[bs,:] . W[e,:] + Wb[e] ), stored bf16
__global__ __launch_bounds__(256, 2) void zgemm_kernel(
    const unsigned short* __restrict__ X, const unsigned short* __restrict__ W,
    const float* __restrict__ Wb, unsigned short* __restrict__ Z)
{
  __shared__ __align__(16) unsigned short lds[2*TILE];   // 32 KiB
  const int bid = blockIdx.x;
  const int tm = bid & 127;          // 128 row tiles (B*S/128)
  const int tn = bid >> 7;           // 8 col tiles (D/128)
  const int tid = threadIdx.x, wave = tid >> 6, lane = tid & 63;
  const int wl = wave >> 1, wn = wave & 1;
  const int g = lane >> 4, cc = lane & 15;

  f32x4 acc[4][4] = {};
#pragma unroll 1
  for (int ks = 0; ks < KST; ++ks){
    __syncthreads();
    stage_tile(X, tm*LT, ks*BK, lds,        wave, lane);
    stage_tile(W, tn*LT, ks*BK, lds + TILE, wave, lane);
    __syncthreads();
#pragma unroll
    for (int ksub = 0; ksub < 2; ++ksub){
      bf16x8 af[4], bfr[4];
#pragma unroll
      for (int f = 0; f < 4; ++f) af[f]  = read_frag(lds,        wl*64 + f*16 + cc, ksub*4 + g);
#pragma unroll
      for (int f = 0; f < 4; ++f) bfr[f] = read_frag(lds + TILE, wn*64 + f*16 + cc, ksub*4 + g);
#pragma unroll
      for (int fm = 0; fm < 4; ++fm)
#pragma unroll
        for (int fn = 0; fn < 4; ++fn)
          acc[fm][fn] = __builtin_amdgcn_mfma_f32_16x16x32_bf16(af[fm], bfr[fn], acc[fm][fn], 0, 0, 0);
    }
  }
#pragma unroll
  for (int fm = 0; fm < 4; ++fm)
#pragma unroll
    for (int fn = 0; fn < 4; ++fn)
#pragma unroll
      for (int r = 0; r < 4; ++r){
        int row = tm*LT + wl*64 + fm*16 + 4*g + r;   // D-frag: row = 4*(lane>>4)+r
        int col = tn*LT + wn*64 + fn*16 + cc;        //         col = lane&15
        float y = acc[fm][fn][r] + Wb[col];
        float e2 = __expf(2.f * y);                  // tanh = 1 - 2/(e^{2y}+1)
        float t = 1.f - 2.f / (e2 + 1.f);            // saturates correctly at +-inf
        Z[(size_t)row*DD + col] = f2bf(t);
      }
}

// fused: per (b, l-tile, s-half): scores=U.Z^T, G=F.X^T, accumulate
// se += sum_s exp(score), ac += sum_s exp(score)*G   (max-free: |score|<~38)
__global__ __launch_bounds__(256, 2) void fused_kernel(
    const unsigned short* __restrict__ U, const unsigned short* __restrict__ F,
    const unsigned short* __restrict__ Z, const unsigned short* __restrict__ X,
    float* __restrict__ pse, float* __restrict__ pac)
{
  __shared__ __align__(16) unsigned short lds[4*TILE];   // 64 KiB
  const int h = blockIdx.x;
  // XCD-grouped swizzle: hardware bid h -> XCD h&7; give each XCD one (b,sp)
  const int logical = (h & 7) * 64 + (h >> 3);
  const int lt  = logical & (NL - 1);
  const int grp = logical >> 6;        // 0..7
  const int sp  = grp & (NS - 1);
  const int b   = grp >> 1;

  const int tid = threadIdx.x, wave = tid >> 6, lane = tid & 63;
  const int wl = wave >> 1, wsc = wave & 1;
  const int g = lane >> 4, cc = lane & 15;

  const unsigned short* Ub = U + (size_t)lt*LT*DD;
  const unsigned short* Fb = F + (size_t)lt*LT*DD;
  const unsigned short* Zb = Z + ((size_t)b*SS + (size_t)sp*SCHUNK) * DD;
  const unsigned short* Xb = X + ((size_t)b*SS + (size_t)sp*SCHUNK) * DD;

  float se_st[4][4] = {}, ac_st[4][4] = {};   // per-lane column-partial sums

#pragma unroll 1
  for (int st = 0; st < NST; ++st){
    f32x4 sacc[4][4] = {}, gacc[4][4] = {};
#pragma unroll 1
    for (int ks = 0; ks < KST; ++ks){
      __syncthreads();
      stage_tile(Ub, 0,     ks*BK, lds,          wave, lane);
      stage_tile(Fb, 0,     ks*BK, lds +   TILE, wave, lane);
      stage_tile(Zb, st*ST, ks*BK, lds + 2*TILE, wave, lane);
      stage_tile(Xb, st*ST, ks*BK, lds + 3*TILE, wave, lane);
      __syncthreads();   // compiler drains vmcnt(0) before s_barrier
#pragma unroll
      for (int ksub = 0; ksub < 2; ++ksub){
        bf16x8 a0[4], b0[4];
#pragma unroll
        for (int f = 0; f < 4; ++f) a0[f] = read_frag(lds,          wl*64  + f*16 + cc, ksub*4 + g);
#pragma unroll
        for (int f = 0; f < 4; ++f) b0[f] = read_frag(lds + 2*TILE, wsc*64 + f*16 + cc, ksub*4 + g);
#pragma unroll
        for (int fm = 0; fm < 4; ++fm)
#pragma unroll
          for (int fn = 0; fn < 4; ++fn)
            sacc[fm][fn] = __builtin_amdgcn_mfma_f32_16x16x32_bf16(a0[fm], b0[fn], sacc[fm][fn], 0, 0, 0);
#pragma unroll
        for (int f = 0; f < 4; ++f) a0[f] = read_frag(lds +   TILE, wl*64  + f*16 + cc, ksub*4 + g);
#pragma unroll
        for (int f = 0; f < 4; ++f) b0[f] = read_frag(lds + 3*TILE, wsc*64 + f*16 + cc, ksub*4 + g);
#pragma unroll
        for (int fm = 0; fm < 4; ++fm)
#pragma unroll
          for (int fn = 0; fn < 4; ++fn)
            gacc[fm][fn] = __builtin_amdgcn_mfma_f32_16x16x32_bf16(a0[fm], b0[fn], gacc[fm][fn], 0, 0, 0);
      }
    }
    // exp-weight and accumulate (keep per-lane column partials; reduce at end)
#pragma unroll
    for (int fm = 0; fm < 4; ++fm)
#pragma unroll
      for (int r = 0; r < 4; ++r){
        float ps = 0.f, pg = 0.f;
#pragma unroll
        for (int fn = 0; fn < 4; ++fn){
          float p = __expf(sacc[fm][fn][r]);
          ps += p;
          pg += p * gacc[fm][fn][r];
        }
        se_st[fm][r] += ps;
        ac_st[fm][r] += pg;
      }
  }
  // reduce across the 16 s-columns held by each lane group, write partials
#pragma unroll
  for (int fm = 0; fm < 4; ++fm)
#pragma unroll
    for (int r = 0; r < 4; ++r){
      float s = se_st[fm][r], a = ac_st[fm][r];
#pragma unroll
      for (int m = 1; m < 16; m <<= 1){
        s += __shfl_xor(s, m, 64);
        a += __shfl_xor(a, m, 64);
      }
      if (cc == 0){
        int l = lt*LT + wl*64 + fm*16 + 4*g + r;
        size_t idx = ((((size_t)b*LL + l)*NS + sp) << 1) + wsc;  // [B][L][NS][2 wave-halves]
        pse[idx] = s;
        pac[idx] = a;
      }
    }
}

__global__ void combine_kernel(const float* __restrict__ pse, const float* __restrict__ pac,
                               const float* __restrict__ fb, float* __restrict__ out)
{
  int i = blockIdx.x*blockDim.x + threadIdx.x;
  if (i >= BB*LL) return;
  int l = i & (LL - 1);
  float s = 0.f, a = 0.f;
#pragma unroll
  for (int k = 0; k < NS*2; ++k){
    s += pse[(size_t)i*(NS*2) + k];
    a += pac[(size_t)i*(NS*2) + k];
  }
  out[i] = a / s + fb[l];
}

extern "C" void kernel_launch(void* const* d_in, const int* in_sizes, int n_in,
                              void* d_out, int out_size, void* d_ws, size_t ws_size,
                              hipStream_t stream)
{
  const float* inp = (const float*)d_in[0];   // [B,S,D]
  const float* Ww  = (const float*)d_in[1];   // [D,D]
  const float* Wb  = (const float*)d_in[2];   // [D]
  const float* Uw  = (const float*)d_in[3];   // [L,D]
  const float* Fw  = (const float*)d_in[4];   // [L,D]
  const float* fb  = (const float*)d_in[5];   // [L]
  float* out = (float*)d_out;

  char* ws = (char*)d_ws;
  unsigned short* Xbf = (unsigned short*)(ws);                            // 32 MiB
  unsigned short* Zbf = (unsigned short*)(ws + (size_t)32*1024*1024);     // 32 MiB
  unsigned short* Ubf = (unsigned short*)(ws + (size_t)64*1024*1024);     // 16 MiB
  unsigned short* Fbf = (unsigned short*)(ws + (size_t)80*1024*1024);     // 16 MiB
  unsigned short* Wbf = (unsigned short*)(ws + (size_t)96*1024*1024);     //  2 MiB
  float* pse = (float*)(ws + (size_t)98*1024*1024);                       // 512 KiB
  float* pac = (float*)(ws + (size_t)99*1024*1024);                       // 512 KiB

  conv_kernel<<<2048, 256, 0, stream>>>((const float4*)inp, (ushort4*)Xbf, BB*SS*DD/4);
  conv_kernel<<<256,  256, 0, stream>>>((const float4*)Ww,  (ushort4*)Wbf, DD*DD/4);
  conv_kernel<<<1024, 256, 0, stream>>>((const float4*)Uw,  (ushort4*)Ubf, LL*DD/4);
  conv_kernel<<<1024, 256, 0, stream>>>((const float4*)Fw,  (ushort4*)Fbf, LL*DD/4);

  zgemm_kernel<<<128*8, 256, 0, stream>>>(Xbf, Wbf, Wb, Zbf);
  fused_kernel<<<BB*NL*NS, 256, 0, stream>>>(Ubf, Fbf, Zbf, Xbf, pse, pac);
  combine_kernel<<<(BB*LL + 255)/256, 256, 0, stream>>>(pse, pac, fb, out);
}